// Round 14
// baseline (869.761 us; speedup 1.0000x reference)
//
#include <hip/hip_runtime.h>

// MHA: out = softmax((qWq^T)(kWk^T)^T/sqrt(128)) (vWv^T) Wo^T + bo
// B=4 T=2048 E=2048 H=16 D=128. All GEMMs via bf16 MFMA (fp32 accum).
// GEMMs: 256x256 tile, BK=64, 8-phase counted-vmcnt schedule, one barrier
// per phase (round-13 best: MfmaUtil ~40%, structural plateau of this
// template at K=2048 / 1 block/CU register-pinned occupancy).
// V produced TRANSPOSED [b,h,d,t]; Q pre-scaled by log2(e)/sqrt(128).

typedef __attribute__((ext_vector_type(4))) float f32x4;
typedef __attribute__((ext_vector_type(2))) float f32x2;
typedef __attribute__((ext_vector_type(8))) __bf16 bf16x8;
typedef __attribute__((ext_vector_type(4))) unsigned int u32x4;
typedef __attribute__((ext_vector_type(2))) unsigned int u32x2;

#define DEVI static __device__ __forceinline__

#define SCQ 0.12751721769f   // log2(e)/sqrt(128)

DEVI unsigned short f2bf(float f) {            // RNE fp32 -> bf16
  union { float f; unsigned u; } x; x.f = f;
  unsigned u = x.u;
  return (unsigned short)((u + 0x7fffu + ((u >> 16) & 1u)) >> 16);
}
DEVI unsigned int pack2(float lo, float hi) {
  return (unsigned int)f2bf(lo) | ((unsigned int)f2bf(hi) << 16);
}
DEVI u32x4 pack8(const f32x4 a, const f32x4 b) {
  u32x4 r;
  r[0] = pack2(a[0], a[1]); r[1] = pack2(a[2], a[3]);
  r[2] = pack2(b[0], b[1]); r[3] = pack2(b[2], b[3]);
  return r;
}
DEVI void gload16(const unsigned short* g, unsigned short* l) {
  __builtin_amdgcn_global_load_lds(
      (const __attribute__((address_space(1))) unsigned int*)g,
      (__attribute__((address_space(3))) unsigned int*)l, 16, 0, 0);
}

// DPP cross-lane (VALU-rate)
template <int CTRL> DEVI float dppf(float x) {
  return __builtin_bit_cast(float, __builtin_amdgcn_update_dpp(
      __builtin_bit_cast(int, x), __builtin_bit_cast(int, x), CTRL, 0xF, 0xF, true));
}
DEVI float rowmax16(float x) {
  x = fmaxf(x, dppf<0x121>(x));
  x = fmaxf(x, dppf<0x122>(x));
  x = fmaxf(x, dppf<0x124>(x));
  x = fmaxf(x, dppf<0x128>(x));
  return x;
}
DEVI float rowsum16(float x) {
  x += dppf<0x121>(x);
  x += dppf<0x122>(x);
  x += dppf<0x124>(x);
  x += dppf<0x128>(x);
  return x;
}

// ---------------------------------------------------------------------------
// fp32 -> bf16 convert, single dispatch. Flat grid 32768 blocks:
// id < 24576: activations (z = id/8192, 16.7M elems each; q scaled by SCQ)
// id >= 24576: weights (zw = (id-24576)/2048, 4.2M elems each)
// ---------------------------------------------------------------------------
__global__ __launch_bounds__(256) void convAll(
    const float* __restrict__ q, const float* __restrict__ k,
    const float* __restrict__ v,
    const float* __restrict__ w0, const float* __restrict__ w1,
    const float* __restrict__ w2, const float* __restrict__ w3,
    unsigned short* __restrict__ dstA, unsigned short* __restrict__ dstW)
{
  const int id = blockIdx.x;
  const float* src;
  unsigned short* dst;
  float scl = 1.0f;
  size_t i;
  if (id < 24576) {
    const int z = id >> 13;                    // 0..2
    src = z == 0 ? q : (z == 1 ? k : v);
    if (z == 0) scl = SCQ;
    dst = dstA + (size_t)z * 16777216;
    i = ((size_t)(id & 8191) * 256 + threadIdx.x) * 8;
  } else {
    const int zw = (id - 24576) >> 11;         // 0..3
    src = zw == 0 ? w0 : (zw == 1 ? w1 : (zw == 2 ? w2 : w3));
    dst = dstW + (size_t)zw * 4194304;
    i = ((size_t)((id - 24576) & 2047) * 256 + threadIdx.x) * 8;
  }
  f32x4 a = *(const f32x4*)(src + i) * scl;
  f32x4 b = *(const f32x4*)(src + i + 4) * scl;
  *(u32x4*)(dst + i) = pack8(a, b);
}

// ---------------------------------------------------------------------------
// 256x256 8-phase GEMM mainloop (round-13, best known). K=2048, BK=64,
// 8 waves (2M x 4N), 512 thr. LDS: [2 buf][256][64] bf16 (128 KB), 16B-slot
// swizzle slot = c^(r&7), source pre-swizzled (0 conflicts measured).
// Stage stream: ph1:A1(t+1) ph2:B0(t+1) ph3:B1(t+1) ph4:A0(t+2)
// ph5:A1(t+2) ph6:B0(t+2) ph7:B1(t+2) ph8:A0(t+3); WVM(2) at ph4/ph8 ends.
// ONE barrier per phase (end). WAR: a region's reads are sealed by the
// barrier after its last read phase (per-wave ds_read -> lgkm -> MFMA ->
// barrier); every restage targets a region sealed >=1 barrier earlier.
// ---------------------------------------------------------------------------
#define STG2(gp, lp, tile) do { \
    gload16((gp) + (size_t)(tile) * 64,            (lp)); \
    gload16((gp) + (size_t)(tile) * 64 + 8 * 2048, (lp) + 8 * 64); \
  } while (0)
#define LDA8(bufoff, ksbit) { \
    _Pragma("unroll") for (int m = 0; m < 8; m++) \
      a[m] = *(const bf16x8*)(As + (bufoff) + (aoff[m] ^ (ksbit))); }
#define LDB2(bufoff, ksbit, n0) { \
    b0 = *(const bf16x8*)(Bs + (bufoff) + (boff[n0] ^ (ksbit))); \
    b1 = *(const bf16x8*)(Bs + (bufoff) + (boff[(n0) + 1] ^ (ksbit))); }
#define MM2(n0) { \
    __builtin_amdgcn_s_setprio(1); \
    _Pragma("unroll") for (int m = 0; m < 8; m++) { \
      acc[m][n0] = __builtin_amdgcn_mfma_f32_16x16x32_bf16(a[m], b0, acc[m][n0], 0, 0, 0); \
      acc[m][(n0) + 1] = __builtin_amdgcn_mfma_f32_16x16x32_bf16(a[m], b1, acc[m][(n0) + 1], 0, 0, 0); \
    } \
    __builtin_amdgcn_s_setprio(0); }
#define BARX() { __builtin_amdgcn_sched_barrier(0); __builtin_amdgcn_s_barrier(); }
#define WVM(n) asm volatile("s_waitcnt vmcnt(" #n ")" ::: "memory");

DEVI void gemm256_bf16(const unsigned short* __restrict__ A,
                       const unsigned short* __restrict__ Bm,
                       unsigned short* As, unsigned short* Bs,
                       int bm, int bn, int tid, f32x4 (&acc)[8][4])
{
  const int lane = tid & 63, w = tid >> 6;
  const int wm = w >> 2, wn = w & 3;
  const int sr = lane >> 3;
  const int sc = (lane & 7) ^ sr;
  const unsigned short* gA0 = A  + (size_t)(bm * 256 +   0 + w * 16 + sr) * 2048 + sc * 8;
  const unsigned short* gA1 = A  + (size_t)(bm * 256 + 128 + w * 16 + sr) * 2048 + sc * 8;
  const unsigned short* gB0 = Bm + (size_t)(bn * 256 +   0 + w * 16 + sr) * 2048 + sc * 8;
  const unsigned short* gB1 = Bm + (size_t)(bn * 256 + 128 + w * 16 + sr) * 2048 + sc * 8;
  unsigned short* lA00 = As +         (  0 + w * 16) * 64;
  unsigned short* lA01 = As +         (128 + w * 16) * 64;
  unsigned short* lA10 = As + 16384 + (  0 + w * 16) * 64;
  unsigned short* lA11 = As + 16384 + (128 + w * 16) * 64;
  unsigned short* lB00 = Bs +         (  0 + w * 16) * 64;
  unsigned short* lB01 = Bs +         (128 + w * 16) * 64;
  unsigned short* lB10 = Bs + 16384 + (  0 + w * 16) * 64;
  unsigned short* lB11 = Bs + 16384 + (128 + w * 16) * 64;

  const int fr = lane & 15, fk = lane >> 4;
  const int swz = (fk ^ (lane & 7)) << 3;
  int aoff[8], boff[4];
#pragma unroll
  for (int m = 0; m < 8; m++) aoff[m] = (wm * 128 + m * 16 + fr) * 64 + swz;
#pragma unroll
  for (int n = 0; n < 4; n++) boff[n] = (wn * 64 + n * 16 + fr) * 64 + swz;

  bf16x8 a[8], b0, b1;

  // prologue: tile0 (buf0) + A0(tile1)->buf1; wait tile0, leave A0(1) in flight
  STG2(gA0, lA00, 0); STG2(gA1, lA01, 0); STG2(gB0, lB00, 0); STG2(gB1, lB01, 0);
  STG2(gA0, lA10, 1);
  WVM(2) BARX()

  for (int t = 0; t < 30; t += 2) {
    // ph1: buf0 ks0 n01 ; stage A1(t+1)->buf1
    LDA8(0, 0) LDB2(0, 0, 0) STG2(gA1, lA11, t + 1);
    MM2(0) BARX()
    // ph2: buf0 ks0 n23 ; stage B0(t+1)->buf1
    LDB2(0, 0, 2) STG2(gB0, lB10, t + 1);
    MM2(2) BARX()
    // ph3: buf0 ks1 n01 ; stage B1(t+1)->buf1   (last A-read of buf0)
    LDA8(0, 32) LDB2(0, 32, 0) STG2(gB1, lB11, t + 1);
    MM2(0) BARX()
    // ph4: buf0 ks1 n23 (last B-read of buf0); stage A0(t+2)->buf0-A
    LDB2(0, 32, 2) STG2(gA0, lA00, t + 2);
    MM2(2) WVM(2) BARX()               // completes trio(t+1) -> buf1 ready
    // ph5: buf1 ks0 n01 ; stage A1(t+2)->buf0
    LDA8(16384, 0) LDB2(16384, 0, 0) STG2(gA1, lA01, t + 2);
    MM2(0) BARX()
    // ph6: buf1 ks0 n23 ; stage B0(t+2)->buf0
    LDB2(16384, 0, 2) STG2(gB0, lB00, t + 2);
    MM2(2) BARX()
    // ph7: buf1 ks1 n01 ; stage B1(t+2)->buf0   (last A-read of buf1)
    LDA8(16384, 32) LDB2(16384, 32, 0) STG2(gB1, lB01, t + 2);
    MM2(0) BARX()
    // ph8: buf1 ks1 n23 (last B-read of buf1); stage A0(t+3)->buf1-A
    LDB2(16384, 32, 2) STG2(gA0, lA10, t + 3);
    MM2(2) WVM(2) BARX()               // completes tile t+2 -> buf0 ready
  }
  // tail: tiles 30 (buf0) and 31 (buf1); trio(31) staged ph1-3, drain at ph4
  LDA8(0, 0) LDB2(0, 0, 0) STG2(gA1, lA11, 31);
  MM2(0) BARX()
  LDB2(0, 0, 2) STG2(gB0, lB10, 31);
  MM2(2) BARX()
  LDA8(0, 32) LDB2(0, 32, 0) STG2(gB1, lB11, 31);
  MM2(0) BARX()
  LDB2(0, 32, 2)
  MM2(2) WVM(0) BARX()
  LDA8(16384, 0) LDB2(16384, 0, 0)
  MM2(0) BARX()
  LDB2(16384, 0, 2)
  MM2(2) BARX()
  LDA8(16384, 32) LDB2(16384, 32, 0)
  MM2(0) BARX()
  LDB2(16384, 32, 2)
  MM2(2)
}

DEVI int xcd_swz256(int bid) { return ((bid & 7) << 5) | (bid >> 3); }

// ---------------------------------------------------------------------------
// Kernel 1: QKV projection. Q,K out [B,H,T,D] (Q pre-scaled via convAll);
// V out TRANSPOSED [B,H,D,T].
// ---------------------------------------------------------------------------
__global__ __launch_bounds__(512, 2) void qkv_gemm_bf(
    const unsigned short* __restrict__ Abf, const unsigned short* __restrict__ Wbf,
    unsigned short* __restrict__ O0, unsigned short* __restrict__ O1,
    unsigned short* __restrict__ O2)
{
  __shared__ unsigned short As[2 * 256 * 64];   // 64 KB
  __shared__ unsigned short Bs[2 * 256 * 64];   // 64 KB
  const int z = blockIdx.z;
  const unsigned short* A = Abf + (size_t)z * 16777216;
  const unsigned short* W = Wbf + (size_t)z * 4194304;
  unsigned short* O = z == 0 ? O0 : (z == 1 ? O1 : O2);

  const int tid = threadIdx.x;
  const int lane = tid & 63, w = tid >> 6;
  const int wm = w >> 2, wn = w & 3;
  const int bs = xcd_swz256(blockIdx.x);
  const int bm = bs >> 3, bn = bs & 7;

  f32x4 acc[8][4];
#pragma unroll
  for (int m = 0; m < 8; m++)
#pragma unroll
    for (int n = 0; n < 4; n++) acc[m][n] = (f32x4)(0.0f);

  gemm256_bf16(A, W, As, Bs, bm, bn, tid, acc);

  if (z == 2) {
    // transposed V epilogue: j=0..3 are 4 consecutive t at fixed d -> 8B store
#pragma unroll
    for (int m = 0; m < 8; m++) {
      int rowg = bm * 256 + wm * 128 + m * 16 + (lane >> 4) * 4;
      int bb = rowg >> 11, t0 = rowg & 2047;
#pragma unroll
      for (int n = 0; n < 4; n++) {
        int col = bn * 256 + wn * 64 + n * 16 + (lane & 15);
        int hh = col >> 7, dd = col & 127;
        u32x2 wv;
        wv[0] = pack2(acc[m][n][0], acc[m][n][1]);
        wv[1] = pack2(acc[m][n][2], acc[m][n][3]);
        *(u32x2*)(O + (((size_t)(bb * 16 + hh) * 128 + dd) << 11) + t0) = wv;
      }
    }
    return;
  }

  const bool evenlane = (lane & 1) == 0;
#pragma unroll
  for (int m = 0; m < 8; m++) {
    int rowg = bm * 256 + wm * 128 + m * 16 + (lane >> 4) * 4;
#pragma unroll
    for (int n = 0; n < 4; n += 2) {
#pragma unroll
      for (int j = 0; j < 4; j++) {
        float v0 = acc[m][n][j], v1 = acc[m][n + 1][j];
        float p0 = __shfl_xor(v0, 1);
        float p1 = __shfl_xor(v1, 1);
        int row = rowg + j;
        int b = row >> 11, t = row & 2047;
        int colbase = bn * 256 + wn * 64;
        int col = evenlane ? (colbase + n * 16 + (lane & 15))
                           : (colbase + (n + 1) * 16 + (lane & 15) - 1);
        unsigned int wv = evenlane ? pack2(v0, p0) : pack2(p1, v1);
        int h = col >> 7, d = col & 127;
        *(unsigned int*)(O + (((size_t)(b * 16 + h) * 2048 + t) << 7) + d) = wv;
      }
    }
  }
}

// ---------------------------------------------------------------------------
// Kernel 3: output projection from bf16 attout + bf16 Wo. fp32 out + bias.
// ---------------------------------------------------------------------------
__global__ __launch_bounds__(512, 2) void out_gemm_bf(
    const unsigned short* __restrict__ Ab, const unsigned short* __restrict__ Wb,
    const float* __restrict__ bias, float* __restrict__ Out)
{
  __shared__ unsigned short As[2 * 256 * 64];
  __shared__ unsigned short Bs[2 * 256 * 64];
  const int tid = threadIdx.x;
  const int lane = tid & 63, w = tid >> 6;
  const int wm = w >> 2, wn = w & 3;
  const int bs = xcd_swz256(blockIdx.x);
  const int bm = bs >> 3, bn = bs & 7;

  f32x4 acc[8][4];
#pragma unroll
  for (int m = 0; m < 8; m++)
#pragma unroll
    for (int n = 0; n < 4; n++) acc[m][n] = (f32x4)(0.0f);

  gemm256_bf16(Ab, Wb, As, Bs, bm, bn, tid, acc);

  float bv[4];
#pragma unroll
  for (int n = 0; n < 4; n++) bv[n] = bias[bn * 256 + wn * 64 + n * 16 + (lane & 15)];
  const bool evenlane = (lane & 1) == 0;
#pragma unroll
  for (int m = 0; m < 8; m++) {
    int rowg = bm * 256 + wm * 128 + m * 16 + (lane >> 4) * 4;
#pragma unroll
    for (int n = 0; n < 4; n += 2) {
#pragma unroll
      for (int j = 0; j < 4; j++) {
        float v0 = acc[m][n][j] + bv[n];
        float v1 = acc[m][n + 1][j] + bv[n + 1];
        float p0 = __shfl_xor(v0, 1);
        float p1 = __shfl_xor(v1, 1);
        int row = rowg + j;
        int colbase = bn * 256 + wn * 64;
        int col = evenlane ? (colbase + n * 16 + (lane & 15))
                           : (colbase + (n + 1) * 16 + (lane & 15) - 1);
        f32x2 wv;
        if (evenlane) { wv[0] = v0; wv[1] = p0; }
        else          { wv[0] = p1; wv[1] = v1; }
        *(f32x2*)(Out + (size_t)row * 2048 + col) = wv;
      }
    }
  }
}

// ---------------------------------------------------------------------------
// Fallback kernel 1: fused QKV with in-kernel pack; Q epilogue-scaled by SCQ;
// V out transposed [B,H,D,T].
// ---------------------------------------------------------------------------
__global__ __launch_bounds__(256) void qkv_gemm(
    const float* __restrict__ A0, const float* __restrict__ A1, const float* __restrict__ A2,
    const float* __restrict__ W0, const float* __restrict__ W1, const float* __restrict__ W2,
    unsigned short* __restrict__ O0, unsigned short* __restrict__ O1, unsigned short* __restrict__ O2)
{
  __shared__ unsigned short Asf[128 * 32];
  __shared__ unsigned short Bsf[128 * 32];
  const int z = blockIdx.z;
  const float* A = z == 0 ? A0 : (z == 1 ? A1 : A2);
  const float* W = z == 0 ? W0 : (z == 1 ? W1 : W2);
  unsigned short* O = z == 0 ? O0 : (z == 1 ? O1 : O2);

  const int tid = threadIdx.x;
  const int lane = tid & 63;
  const int wave = tid >> 6;
  const int wm = wave >> 1, wn = wave & 1;
  const int bm = blockIdx.x >> 4, bn = blockIdx.x & 15;

  const int srow = tid >> 1;
  const int shalf = tid & 1;
  const float* Ap = A + (size_t)(bm * 128 + srow) * 2048 + shalf * 16;
  const float* Wp = W + (size_t)(bn * 128 + srow) * 2048 + shalf * 16;
  const int ssw = (srow >> 1) & 3;
  const int aoff0 = srow * 32 + (((shalf * 2 + 0) ^ ssw) << 3);
  const int aoff1 = srow * 32 + (((shalf * 2 + 1) ^ ssw) << 3);

  const int frow = lane & 15;
  const int fk = lane >> 4;

  f32x4 acc[4][4];
#pragma unroll
  for (int m = 0; m < 4; m++)
#pragma unroll
    for (int n = 0; n < 4; n++) acc[m][n] = (f32x4)(0.0f);

  for (int kk = 0; kk < 2048; kk += 32) {
    f32x4 a0 = *(const f32x4*)(Ap + kk);
    f32x4 a1 = *(const f32x4*)(Ap + kk + 4);
    f32x4 a2 = *(const f32x4*)(Ap + kk + 8);
    f32x4 a3 = *(const f32x4*)(Ap + kk + 12);
    f32x4 b0 = *(const f32x4*)(Wp + kk);
    f32x4 b1 = *(const f32x4*)(Wp + kk + 4);
    f32x4 b2 = *(const f32x4*)(Wp + kk + 8);
    f32x4 b3 = *(const f32x4*)(Wp + kk + 12);
    __syncthreads();
    *(u32x4*)(Asf + aoff0) = pack8(a0, a1);
    *(u32x4*)(Asf + aoff1) = pack8(a2, a3);
    *(u32x4*)(Bsf + aoff0) = pack8(b0, b1);
    *(u32x4*)(Bsf + aoff1) = pack8(b2, b3);
    __syncthreads();
    bf16x8 af[4], bfr[4];
#pragma unroll
    for (int m = 0; m < 4; m++) {
      int r = wm * 64 + m * 16 + frow;
      af[m] = *(const bf16x8*)(Asf + r * 32 + ((fk ^ ((r >> 1) & 3)) << 3));
    }
#pragma unroll
    for (int n = 0; n < 4; n++) {
      int r = wn * 64 + n * 16 + frow;
      bfr[n] = *(const bf16x8*)(Bsf + r * 32 + ((fk ^ ((r >> 1) & 3)) << 3));
    }
#pragma unroll
    for (int m = 0; m < 4; m++)
#pragma unroll
      for (int n = 0; n < 4; n++)
        acc[m][n] = __builtin_amdgcn_mfma_f32_16x16x32_bf16(af[m], bfr[n], acc[m][n], 0, 0, 0);
  }

  if (z == 2) {
#pragma unroll
    for (int m = 0; m < 4; m++) {
      int rowg = bm * 128 + wm * 64 + m * 16 + (lane >> 4) * 4;
      int bb = rowg >> 11, t0 = rowg & 2047;
#pragma unroll
      for (int n = 0; n < 4; n++) {
        int col = bn * 128 + wn * 64 + n * 16 + (lane & 15);
        int hh = col >> 7, dd = col & 127;
        u32x2 wv;
        wv[0] = pack2(acc[m][n][0], acc[m][n][1]);
        wv[1] = pack2(acc[m][n][2], acc[m][n][3]);
        *(u32x2*)(O + (((size_t)(bb * 16 + hh) * 128 + dd) << 11) + t0) = wv;
      }
    }
    return;
  }

  const float scl = (z == 0) ? SCQ : 1.0f;
  const bool evenlane = (lane & 1) == 0;
#pragma unroll
  for (int m = 0; m < 4; m++) {
    int rowg = bm * 128 + wm * 64 + m * 16 + (lane >> 4) * 4;
#pragma unroll
    for (int n = 0; n < 4; n += 2) {
#pragma unroll
      for (int j = 0; j < 4; j++) {
        float v0 = acc[m][n][j] * scl, v1 = acc[m][n + 1][j] * scl;
        float p0 = __shfl_xor(v0, 1);
        float p1 = __shfl_xor(v1, 1);
        int row = rowg + j;
        int b = row >> 11, t = row & 2047;
        int colbase = bn * 128 + wn * 64;
        int col = evenlane ? (colbase + n * 16 + (lane & 15))
                           : (colbase + (n + 1) * 16 + (lane & 15) - 1);
        unsigned int wv = evenlane ? pack2(v0, p0) : pack2(p1, v1);
        int h = col >> 7, d = col & 127;
        *(unsigned int*)(O + (((size_t)(b * 16 + h) * 2048 + t) << 7) + d) = wv;
      }
    }
  }
}

// ---------------------------------------------------------------------------
// Kernel 2: flash attention v5 (round-8 structure), last KV tile peeled so
// the main loop stages unconditionally. Log2-space softmax, local-max defer,
// per-lane partial l, V^T via global_load_lds.
// ---------------------------------------------------------------------------
__global__ __launch_bounds__(256, 2) void attn(
    const unsigned short* __restrict__ Qw, const unsigned short* __restrict__ Kw,
    const unsigned short* __restrict__ VwT, unsigned short* __restrict__ attout)
{
  __shared__ unsigned short Ks[2][64 * 128];
  __shared__ unsigned short Vs[2][128 * 64];
  __shared__ unsigned short Ps[128 * 64];

  const int bid = blockIdx.x;
  const int work = ((bid & 7) << 7) | (bid >> 3);
  const int bh = work >> 4;
  const int qtile = work & 15;
  const int b = bh >> 4, h = bh & 15;
  const unsigned short* Qbase = Qw + (size_t)bh * 2048 * 128 + qtile * 128 * 128;
  const unsigned short* Kbase = Kw + (size_t)bh * 2048 * 128;
  const unsigned short* VbaseT = VwT + (size_t)bh * 2048 * 128;
  const int tid = threadIdx.x, lane = tid & 63, w = tid >> 6;
  const int frow = lane & 15, fk = lane >> 4;

  bf16x8 qf[2][4];
#pragma unroll
  for (int m = 0; m < 2; m++)
#pragma unroll
    for (int ks = 0; ks < 4; ks++)
      qf[m][ks] = *(const bf16x8*)(Qbase + (size_t)(w * 32 + m * 16 + frow) * 128 + ks * 32 + fk * 8);

  const int krow_i = lane >> 4;
  const int kslot = lane & 15;
  const int vrow_i = lane >> 3;
  const int vslot = (lane & 7) ^ vrow_i;

  f32x4 o[2][8];
#pragma unroll
  for (int m = 0; m < 2; m++)
#pragma unroll
    for (int n = 0; n < 8; n++) o[m][n] = (f32x4)(0.0f);
  float m_r[2][4], l_p[2][4];
#pragma unroll
  for (int m = 0; m < 2; m++)
#pragma unroll
    for (int j = 0; j < 4; j++) { m_r[m][j] = -INFINITY; l_p[m][j] = 0.f; }
  const float THRL = 11.5f;

  // per-tile compute body (S = QK^T, online softmax, P pack, O += PV)
#define ATTN_TILE(CUR)                                                         \
  {                                                                            \
    f32x4 s[2][4];                                                             \
    __builtin_amdgcn_s_setprio(1);                                             \
    _Pragma("unroll")                                                          \
    for (int n = 0; n < 4; n++) {                                              \
      int brow = n * 16 + frow;                                                \
      bf16x8 bk = *(const bf16x8*)(&Ks[CUR][0] + brow * 128 +                  \
                                   ((fk ^ (brow & 15)) << 3));                 \
      _Pragma("unroll")                                                        \
      for (int m = 0; m < 2; m++)                                              \
        s[m][n] = __builtin_amdgcn_mfma_f32_16x16x32_bf16(                     \
            qf[m][0], bk, (f32x4)(0.0f), 0, 0, 0);                             \
    }                                                                          \
    _Pragma("unroll")                                                          \
    for (int ks = 1; ks < 4; ks++) {                                           \
      _Pragma("unroll")                                                        \
      for (int n = 0; n < 4; n++) {                                            \
        int brow = n * 16 + frow;                                              \
        bf16x8 bk = *(const bf16x8*)(&Ks[CUR][0] + brow * 128 +                \
                                     (((ks * 4 + fk) ^ (brow & 15)) << 3));    \
        _Pragma("unroll")                                                      \
        for (int m = 0; m < 2; m++)                                            \
          s[m][n] = __builtin_amdgcn_mfma_f32_16x16x32_bf16(                   \
              qf[m][ks], bk, s[m][n], 0, 0, 0);                                \
      }                                                                        \
    }                                                                          \
    __builtin_amdgcn_s_setprio(0);                                             \
    _Pragma("unroll")                                                          \
    for (int m = 0; m < 2; m++) {                                              \
      _Pragma("unroll")                                                        \
      for (int j = 0; j < 4; j++) {                                            \
        float mx = fmaxf(fmaxf(s[m][0][j], s[m][1][j]),                        \
                         fmaxf(s[m][2][j], s[m][3][j]));                       \
        float mo = m_r[m][j];                                                  \
        if (!__all(mx - mo <= THRL)) {                                         \
          float mnew = fmaxf(mo, rowmax16(mx));                                \
          float f = __builtin_amdgcn_exp2f(mo - mnew);                         \
          m_r[m][j] = mnew;                                                    \
          l_p[m][j] *= f;                                                      \
          _Pragma("unroll")                                                    \
          for (int n = 0; n < 8; n++) o[m][n][j] *= f;                         \
        }                                                                      \
        float mm = m_r[m][j];                                                  \
        float ps = 0.f;                                                        \
        _Pragma("unroll")                                                      \
        for (int n = 0; n < 4; n++) {                                          \
          float p = __builtin_amdgcn_exp2f(s[m][n][j] - mm);                   \
          s[m][n][j] = p;                                                      \
          ps += p;                                                             \
        }                                                                      \
        l_p[m][j] += ps;                                                       \
        int row = w * 32 + m * 16 + (lane >> 4) * 4 + j;                       \
        int swzp = row & 7;                                                    \
        unsigned prv[4];                                                       \
        _Pragma("unroll")                                                      \
        for (int n = 0; n < 4; n++) {                                          \
          float p = s[m][n][j];                                                \
          float ph = dppf<0xB1>(p);                                            \
          unsigned pr;                                                         \
          asm("v_cvt_pk_bf16_f32 %0, %1, %2" : "=v"(pr) : "v"(p), "v"(ph));    \
          prv[n] = pr;                                                         \
        }                                                                      \
        if (!(lane & 1)) {                                                     \
          _Pragma("unroll")                                                    \
          for (int n = 0; n < 4; n++) {                                        \
            int col = frow + 16 * n;                                           \
            *(unsigned*)((char*)Ps + row * 128 +                               \
                         (((col >> 3) ^ swzp) << 4) + (col & 7) * 2) = prv[n]; \
          }                                                                    \
        }                                                                      \
      }                                                                        \
    }                                                                          \
    __builtin_amdgcn_s_setprio(1);                                             \
    _Pragma("unroll")                                                          \
    for (int ks = 0; ks < 2; ks++) {                                           \
      bf16x8 ap[2];                                                            \
      _Pragma("unroll")                                                        \
      for (int m = 0; m < 2; m++) {                                            \
        int arow = w * 32 + m * 16 + frow;                                     \
        ap[m] = *(const bf16x8*)((char*)Ps + arow * 128 +                      \
                                 (((ks * 4 + fk) ^ (arow & 7)) << 4));         \
      }                                                                        \
      _Pragma("unroll")                                                        \
      for (int n = 0; n < 8; n++) {                                            \
        int vrow = n * 16 + frow;                                              \
        bf16x8 bv = *(const bf16x8*)((char*)&Vs[CUR][0] + vrow * 128 +         \
                                     (((ks * 4 + fk) ^ (vrow & 7)) << 4));     \
        _Pragma("unroll")                                                      \
        for (int m = 0; m < 2; m++)                                            \
          o[m][n] = __builtin_amdgcn_mfma_f32_16x16x32_bf16(                   \
              ap[m], bv, o[m][n], 0, 0, 0);                                    \
      }                                                                        \
    }                                                                          \
    __builtin_amdgcn_s_setprio(0);                                             \
  }

  // prologue: stage tile 0
  {
#pragma unroll
    for (int i = 0; i < 4; i++) {
      int row = w * 16 + i * 4 + krow_i;
      gload16(Kbase + (size_t)row * 128 + ((kslot ^ (row & 15)) << 3),
              &Ks[0][(w * 16 + i * 4) * 128]);
    }
#pragma unroll
    for (int i = 0; i < 4; i++) {
      int d = w * 32 + i * 8 + vrow_i;
      gload16(VbaseT + (size_t)d * 2048 + vslot * 8,
              &Vs[0][(w * 32 + i * 8) * 64]);
    }
  }

  for (int kt = 0; kt < 31; kt++) {     // main loop: always stages kt+1
    const int cur = kt & 1;
    __syncthreads();
    const unsigned short* Kt = Kbase + (kt + 1) * 64 * 128;
#pragma unroll
    for (int i = 0; i < 4; i++) {
      int row = w * 16 + i * 4 + krow_i;
      gload16(Kt + (size_t)row * 128 + ((kslot ^ (row & 15)) << 3),
              &Ks[cur ^ 1][(w * 16 + i * 4) * 128]);
    }
#pragma unroll
    for (int i = 0; i < 4; i++) {
      int d = w * 32 + i * 8 + vrow_i;
      gload16(VbaseT + (size_t)d * 2048 + (kt + 1) * 64 + vslot * 8,
              &Vs[cur ^ 1][(w * 32 + i * 8) * 64]);
    }
    if (cur == 0) ATTN_TILE(0) else ATTN_TILE(1)
  }
  // peeled final tile (kt=31, buf 1)
  __syncthreads();
  ATTN_TILE(1)
#undef ATTN_TILE

  const bool evenlane = (lane & 1) == 0;
#pragma unroll
  for (int m = 0; m < 2; m++) {
    float inv[4];
#pragma unroll
    for (int j = 0; j < 4; j++) inv[j] = 1.0f / rowsum16(l_p[m][j]);
#pragma unroll
    for (int n = 0; n < 8; n += 2) {
#pragma unroll
      for (int j = 0; j < 4; j++) {
        float v0 = o[m][n][j] * inv[j], v1 = o[m][n + 1][j] * inv[j];
        float p0 = __shfl_xor(v0, 1);
        float p1 = __shfl_xor(v1, 1);
        int tq = qtile * 128 + w * 32 + m * 16 + (lane >> 4) * 4 + j;
        int col = evenlane ? (n * 16 + (lane & 15)) : ((n + 1) * 16 + (lane & 15) - 1);
        unsigned int wv = evenlane ? pack2(v0, p0) : pack2(p1, v1);
        *(unsigned int*)(attout + (size_t)(b * 2048 + tq) * 2048 + h * 128 + col) = wv;
      }
    }
  }
}

// ---------------------------------------------------------------------------
// Fallback kernel 3 (round-1): output projection with in-kernel fp32 W pack.
// ---------------------------------------------------------------------------
__global__ __launch_bounds__(256) void out_gemm(
    const unsigned short* __restrict__ Ab, const float* __restrict__ W,
    const float* __restrict__ bias, float* __restrict__ Out)
{
  __shared__ unsigned short Asf[128 * 32];
  __shared__ unsigned short Bsf[128 * 32];

  const int tid = threadIdx.x;
  const int lane = tid & 63;
  const int wave = tid >> 6;
  const int wm = wave >> 1, wn = wave & 1;
  const int bm = blockIdx.x >> 4, bn = blockIdx.x & 15;

  const int srow = tid >> 1;
  const int shalf = tid & 1;
  const unsigned short* Ap = Ab + (size_t)(bm * 128 + srow) * 2048 + shalf * 16;
  const float* Wp = W + (size_t)(bn * 128 + srow) * 2048 + shalf * 16;
  const int ssw = (srow >> 1) & 3;
  const int aoff0 = srow * 32 + (((shalf * 2 + 0) ^ ssw) << 3);
  const int aoff1 = srow * 32 + (((shalf * 2 + 1) ^ ssw) << 3);

  const int frow = lane & 15;
  const int fk = lane >> 4;

  f32x4 acc[4][4];
#pragma unroll
  for (int m = 0; m < 4; m++)
#pragma unroll
    for (int n = 0; n < 4; n++) acc[m][n] = (f32x4)(0.0f);

  for (int kk = 0; kk < 2048; kk += 32) {
    u32x4 a0 = *(const u32x4*)(Ap + kk);
    u32x4 a1 = *(const u32x4*)(Ap + kk + 8);
    f32x4 b0 = *(const f32x4*)(Wp + kk);
    f32x4 b1 = *(const f32x4*)(Wp + kk + 4);
    f32x4 b2 = *(const f32x4*)(Wp + kk + 8);
    f32x4 b3 = *(const f32x4*)(Wp + kk + 12);
    __syncthreads();
    *(u32x4*)(Asf + aoff0) = a0;
    *(u32x4*)(Asf + aoff1) = a1;
    *(u32x4*)(Bsf + aoff0) = pack8(b0, b1);
    *(u32x4*)(Bsf + aoff1) = pack8(b2, b3);
    __syncthreads();
    bf16x8 af[4], bfr[4];
#pragma unroll
    for (int m = 0; m < 4; m++) {
      int r = wm * 64 + m * 16 + frow;
      af[m] = *(const bf16x8*)(Asf + r * 32 + ((fk ^ ((r >> 1) & 3)) << 3));
    }
#pragma unroll
    for (int n = 0; n < 4; n++) {
      int r = wn * 64 + n * 16 + frow;
      bfr[n] = *(const bf16x8*)(Bsf + r * 32 + ((fk ^ ((r >> 1) & 3)) << 3));
    }
#pragma unroll
    for (int m = 0; m < 4; m++)
#pragma unroll
      for (int n = 0; n < 4; n++)
        acc[m][n] = __builtin_amdgcn_mfma_f32_16x16x32_bf16(af[m], bfr[n], acc[m][n], 0, 0, 0);
  }

  float bv[4];
#pragma unroll
  for (int n = 0; n < 4; n++) bv[n] = bias[bn * 128 + wn * 64 + n * 16 + (lane & 15)];
  const bool evenlane = (lane & 1) == 0;
#pragma unroll
  for (int m = 0; m < 4; m++) {
    int rowg = bm * 128 + wm * 64 + m * 16 + (lane >> 4) * 4;
#pragma unroll
    for (int n = 0; n < 4; n += 2) {
#pragma unroll
      for (int j = 0; j < 4; j++) {
        float v0 = acc[m][n][j] + bv[n];
        float v1 = acc[m][n + 1][j] + bv[n + 1];
        float p0 = __shfl_xor(v0, 1);
        float p1 = __shfl_xor(v1, 1);
        int row = rowg + j;
        int colbase = bn * 128 + wn * 64;
        int col = evenlane ? (colbase + n * 16 + (lane & 15))
                           : (colbase + (n + 1) * 16 + (lane & 15) - 1);
        f32x2 wv;
        if (evenlane) { wv[0] = v0; wv[1] = p0; }
        else          { wv[0] = p1; wv[1] = v1; }
        *(f32x2*)(Out + (size_t)row * 2048 + col) = wv;
      }
    }
  }
}

// ---------------------------------------------------------------------------
extern "C" void kernel_launch(void* const* d_in, const int* in_sizes, int n_in,
                              void* d_out, int out_size, void* d_ws, size_t ws_size,
                              hipStream_t stream)
{
  // setup_inputs order: k, q, v, Wk, Wq, Wv, Wo, bo
  const float* k  = (const float*)d_in[0];
  const float* q  = (const float*)d_in[1];
  const float* v  = (const float*)d_in[2];
  const float* Wk = (const float*)d_in[3];
  const float* Wq = (const float*)d_in[4];
  const float* Wv = (const float*)d_in[5];
  const float* Wo = (const float*)d_in[6];
  const float* bo = (const float*)d_in[7];
  float* out = (float*)d_out;

  const size_t HSZ = (size_t)4 * 16 * 2048 * 128;   // 32 MiB (bf16 elems)

  if (ws_size >= (size_t)224 << 20) {
    unsigned short* Abf = (unsigned short*)d_ws;
    unsigned short* Wbf = Abf + 3 * HSZ;
    unsigned short* Qw  = Wbf + 4 * 4194304;
    unsigned short* Kw  = Qw + HSZ;
    unsigned short* Vw  = Kw + HSZ;       // V stored TRANSPOSED [b,h,d,t]
    unsigned short* Aw  = Abf;

    convAll<<<dim3(32768), 256, 0, stream>>>(q, k, v, Wq, Wk, Wv, Wo, Abf, Wbf);
    qkv_gemm_bf<<<dim3(256, 1, 3), 512, 0, stream>>>(Abf, Wbf, Qw, Kw, Vw);
    attn<<<dim3(1024), 256, 0, stream>>>(Qw, Kw, Vw, Aw);
    out_gemm_bf<<<dim3(256), 512, 0, stream>>>(Aw, Wbf + 3 * 4194304, bo, out);
  } else {
    unsigned short* Qw = (unsigned short*)d_ws;
    unsigned short* Kw = Qw + HSZ;
    unsigned short* Vw = Kw + HSZ;        // transposed V here too
    unsigned short* Aw = Vw + HSZ;
    qkv_gemm<<<dim3(1024, 1, 3), 256, 0, stream>>>(q, k, v, Wq, Wk, Wv, Qw, Kw, Vw);
    attn<<<dim3(1024), 256, 0, stream>>>(Qw, Kw, Vw, Aw);
    out_gemm<<<dim3(1024), 256, 0, stream>>>(Aw, Wo, bo, out);
  }
}

// Round 15
// 514.811 us; speedup vs baseline: 1.6895x; 1.6895x over previous
//
#include <hip/hip_runtime.h>

// MHA: out = softmax((qWq^T)(kWk^T)^T/sqrt(128)) (vWv^T) Wo^T + bo
// B=4 T=2048 E=2048 H=16 D=128. All GEMMs via bf16 MFMA (fp32 accum).
// GEMMs: 256x256 tile, BK=64, 8-phase counted-vmcnt, one barrier per phase
// (round-13 best). attn: round-8 flash attention (round-14's peeled/macro
// variant spilled: branch-duplicated body -> 150MB scratch, reverted).
// V produced TRANSPOSED [b,h,d,t]; Q pre-scaled by log2(e)/sqrt(128).

typedef __attribute__((ext_vector_type(4))) float f32x4;
typedef __attribute__((ext_vector_type(2))) float f32x2;
typedef __attribute__((ext_vector_type(8))) __bf16 bf16x8;
typedef __attribute__((ext_vector_type(4))) unsigned int u32x4;
typedef __attribute__((ext_vector_type(2))) unsigned int u32x2;

#define DEVI static __device__ __forceinline__

#define SCQ 0.12751721769f   // log2(e)/sqrt(128)

DEVI unsigned short f2bf(float f) {            // RNE fp32 -> bf16
  union { float f; unsigned u; } x; x.f = f;
  unsigned u = x.u;
  return (unsigned short)((u + 0x7fffu + ((u >> 16) & 1u)) >> 16);
}
DEVI unsigned int pack2(float lo, float hi) {
  return (unsigned int)f2bf(lo) | ((unsigned int)f2bf(hi) << 16);
}
DEVI u32x4 pack8(const f32x4 a, const f32x4 b) {
  u32x4 r;
  r[0] = pack2(a[0], a[1]); r[1] = pack2(a[2], a[3]);
  r[2] = pack2(b[0], b[1]); r[3] = pack2(b[2], b[3]);
  return r;
}
DEVI void gload16(const unsigned short* g, unsigned short* l) {
  __builtin_amdgcn_global_load_lds(
      (const __attribute__((address_space(1))) unsigned int*)g,
      (__attribute__((address_space(3))) unsigned int*)l, 16, 0, 0);
}

// DPP cross-lane (VALU-rate)
template <int CTRL> DEVI float dppf(float x) {
  return __builtin_bit_cast(float, __builtin_amdgcn_update_dpp(
      __builtin_bit_cast(int, x), __builtin_bit_cast(int, x), CTRL, 0xF, 0xF, true));
}
DEVI float rowmax16(float x) {
  x = fmaxf(x, dppf<0x121>(x));
  x = fmaxf(x, dppf<0x122>(x));
  x = fmaxf(x, dppf<0x124>(x));
  x = fmaxf(x, dppf<0x128>(x));
  return x;
}
DEVI float rowsum16(float x) {
  x += dppf<0x121>(x);
  x += dppf<0x122>(x);
  x += dppf<0x124>(x);
  x += dppf<0x128>(x);
  return x;
}

// ---------------------------------------------------------------------------
// fp32 -> bf16 convert, single dispatch. Flat grid 32768 blocks:
// id < 24576: activations (z = id/8192; q scaled by SCQ); else weights.
// ---------------------------------------------------------------------------
__global__ __launch_bounds__(256) void convAll(
    const float* __restrict__ q, const float* __restrict__ k,
    const float* __restrict__ v,
    const float* __restrict__ w0, const float* __restrict__ w1,
    const float* __restrict__ w2, const float* __restrict__ w3,
    unsigned short* __restrict__ dstA, unsigned short* __restrict__ dstW)
{
  const int id = blockIdx.x;
  const float* src;
  unsigned short* dst;
  float scl = 1.0f;
  size_t i;
  if (id < 24576) {
    const int z = id >> 13;                    // 0..2
    src = z == 0 ? q : (z == 1 ? k : v);
    if (z == 0) scl = SCQ;
    dst = dstA + (size_t)z * 16777216;
    i = ((size_t)(id & 8191) * 256 + threadIdx.x) * 8;
  } else {
    const int zw = (id - 24576) >> 11;         // 0..3
    src = zw == 0 ? w0 : (zw == 1 ? w1 : (zw == 2 ? w2 : w3));
    dst = dstW + (size_t)zw * 4194304;
    i = ((size_t)((id - 24576) & 2047) * 256 + threadIdx.x) * 8;
  }
  f32x4 a = *(const f32x4*)(src + i) * scl;
  f32x4 b = *(const f32x4*)(src + i + 4) * scl;
  *(u32x4*)(dst + i) = pack8(a, b);
}

// ---------------------------------------------------------------------------
// 256x256 8-phase GEMM mainloop (round-13, best known). K=2048, BK=64,
// 8 waves (2M x 4N), 512 thr. LDS: [2 buf][256][64] bf16 (128 KB), 16B-slot
// swizzle slot = c^(r&7), source pre-swizzled (0 conflicts measured).
// Stage stream: ph1:A1(t+1) ph2:B0(t+1) ph3:B1(t+1) ph4:A0(t+2)
// ph5:A1(t+2) ph6:B0(t+2) ph7:B1(t+2) ph8:A0(t+3); WVM(2) at ph4/ph8 ends.
// ONE barrier per phase (end).
// ---------------------------------------------------------------------------
#define STG2(gp, lp, tile) do { \
    gload16((gp) + (size_t)(tile) * 64,            (lp)); \
    gload16((gp) + (size_t)(tile) * 64 + 8 * 2048, (lp) + 8 * 64); \
  } while (0)
#define LDA8(bufoff, ksbit) { \
    _Pragma("unroll") for (int m = 0; m < 8; m++) \
      a[m] = *(const bf16x8*)(As + (bufoff) + (aoff[m] ^ (ksbit))); }
#define LDB2(bufoff, ksbit, n0) { \
    b0 = *(const bf16x8*)(Bs + (bufoff) + (boff[n0] ^ (ksbit))); \
    b1 = *(const bf16x8*)(Bs + (bufoff) + (boff[(n0) + 1] ^ (ksbit))); }
#define MM2(n0) { \
    __builtin_amdgcn_s_setprio(1); \
    _Pragma("unroll") for (int m = 0; m < 8; m++) { \
      acc[m][n0] = __builtin_amdgcn_mfma_f32_16x16x32_bf16(a[m], b0, acc[m][n0], 0, 0, 0); \
      acc[m][(n0) + 1] = __builtin_amdgcn_mfma_f32_16x16x32_bf16(a[m], b1, acc[m][(n0) + 1], 0, 0, 0); \
    } \
    __builtin_amdgcn_s_setprio(0); }
#define BARX() { __builtin_amdgcn_sched_barrier(0); __builtin_amdgcn_s_barrier(); }
#define WVM(n) asm volatile("s_waitcnt vmcnt(" #n ")" ::: "memory");

DEVI void gemm256_bf16(const unsigned short* __restrict__ A,
                       const unsigned short* __restrict__ Bm,
                       unsigned short* As, unsigned short* Bs,
                       int bm, int bn, int tid, f32x4 (&acc)[8][4])
{
  const int lane = tid & 63, w = tid >> 6;
  const int wm = w >> 2, wn = w & 3;
  const int sr = lane >> 3;
  const int sc = (lane & 7) ^ sr;
  const unsigned short* gA0 = A  + (size_t)(bm * 256 +   0 + w * 16 + sr) * 2048 + sc * 8;
  const unsigned short* gA1 = A  + (size_t)(bm * 256 + 128 + w * 16 + sr) * 2048 + sc * 8;
  const unsigned short* gB0 = Bm + (size_t)(bn * 256 +   0 + w * 16 + sr) * 2048 + sc * 8;
  const unsigned short* gB1 = Bm + (size_t)(bn * 256 + 128 + w * 16 + sr) * 2048 + sc * 8;
  unsigned short* lA00 = As +         (  0 + w * 16) * 64;
  unsigned short* lA01 = As +         (128 + w * 16) * 64;
  unsigned short* lA10 = As + 16384 + (  0 + w * 16) * 64;
  unsigned short* lA11 = As + 16384 + (128 + w * 16) * 64;
  unsigned short* lB00 = Bs +         (  0 + w * 16) * 64;
  unsigned short* lB01 = Bs +         (128 + w * 16) * 64;
  unsigned short* lB10 = Bs + 16384 + (  0 + w * 16) * 64;
  unsigned short* lB11 = Bs + 16384 + (128 + w * 16) * 64;

  const int fr = lane & 15, fk = lane >> 4;
  const int swz = (fk ^ (lane & 7)) << 3;
  int aoff[8], boff[4];
#pragma unroll
  for (int m = 0; m < 8; m++) aoff[m] = (wm * 128 + m * 16 + fr) * 64 + swz;
#pragma unroll
  for (int n = 0; n < 4; n++) boff[n] = (wn * 64 + n * 16 + fr) * 64 + swz;

  bf16x8 a[8], b0, b1;

  // prologue: tile0 (buf0) + A0(tile1)->buf1; wait tile0, leave A0(1) in flight
  STG2(gA0, lA00, 0); STG2(gA1, lA01, 0); STG2(gB0, lB00, 0); STG2(gB1, lB01, 0);
  STG2(gA0, lA10, 1);
  WVM(2) BARX()

  for (int t = 0; t < 30; t += 2) {
    LDA8(0, 0) LDB2(0, 0, 0) STG2(gA1, lA11, t + 1);
    MM2(0) BARX()
    LDB2(0, 0, 2) STG2(gB0, lB10, t + 1);
    MM2(2) BARX()
    LDA8(0, 32) LDB2(0, 32, 0) STG2(gB1, lB11, t + 1);
    MM2(0) BARX()
    LDB2(0, 32, 2) STG2(gA0, lA00, t + 2);
    MM2(2) WVM(2) BARX()               // completes trio(t+1) -> buf1 ready
    LDA8(16384, 0) LDB2(16384, 0, 0) STG2(gA1, lA01, t + 2);
    MM2(0) BARX()
    LDB2(16384, 0, 2) STG2(gB0, lB00, t + 2);
    MM2(2) BARX()
    LDA8(16384, 32) LDB2(16384, 32, 0) STG2(gB1, lB01, t + 2);
    MM2(0) BARX()
    LDB2(16384, 32, 2) STG2(gA0, lA10, t + 3);
    MM2(2) WVM(2) BARX()               // completes tile t+2 -> buf0 ready
  }
  LDA8(0, 0) LDB2(0, 0, 0) STG2(gA1, lA11, 31);
  MM2(0) BARX()
  LDB2(0, 0, 2) STG2(gB0, lB10, 31);
  MM2(2) BARX()
  LDA8(0, 32) LDB2(0, 32, 0) STG2(gB1, lB11, 31);
  MM2(0) BARX()
  LDB2(0, 32, 2)
  MM2(2) WVM(0) BARX()
  LDA8(16384, 0) LDB2(16384, 0, 0)
  MM2(0) BARX()
  LDB2(16384, 0, 2)
  MM2(2) BARX()
  LDA8(16384, 32) LDB2(16384, 32, 0)
  MM2(0) BARX()
  LDB2(16384, 32, 2)
  MM2(2)
}

DEVI int xcd_swz256(int bid) { return ((bid & 7) << 5) | (bid >> 3); }

// ---------------------------------------------------------------------------
// Kernel 1: QKV projection. Q,K out [B,H,T,D] (Q pre-scaled via convAll);
// V out TRANSPOSED [B,H,D,T].
// ---------------------------------------------------------------------------
__global__ __launch_bounds__(512, 2) void qkv_gemm_bf(
    const unsigned short* __restrict__ Abf, const unsigned short* __restrict__ Wbf,
    unsigned short* __restrict__ O0, unsigned short* __restrict__ O1,
    unsigned short* __restrict__ O2)
{
  __shared__ unsigned short As[2 * 256 * 64];   // 64 KB
  __shared__ unsigned short Bs[2 * 256 * 64];   // 64 KB
  const int z = blockIdx.z;
  const unsigned short* A = Abf + (size_t)z * 16777216;
  const unsigned short* W = Wbf + (size_t)z * 4194304;
  unsigned short* O = z == 0 ? O0 : (z == 1 ? O1 : O2);

  const int tid = threadIdx.x;
  const int lane = tid & 63, w = tid >> 6;
  const int wm = w >> 2, wn = w & 3;
  const int bs = xcd_swz256(blockIdx.x);
  const int bm = bs >> 3, bn = bs & 7;

  f32x4 acc[8][4];
#pragma unroll
  for (int m = 0; m < 8; m++)
#pragma unroll
    for (int n = 0; n < 4; n++) acc[m][n] = (f32x4)(0.0f);

  gemm256_bf16(A, W, As, Bs, bm, bn, tid, acc);

  if (z == 2) {
    // transposed V epilogue: j=0..3 are 4 consecutive t at fixed d -> 8B store
#pragma unroll
    for (int m = 0; m < 8; m++) {
      int rowg = bm * 256 + wm * 128 + m * 16 + (lane >> 4) * 4;
      int bb = rowg >> 11, t0 = rowg & 2047;
#pragma unroll
      for (int n = 0; n < 4; n++) {
        int col = bn * 256 + wn * 64 + n * 16 + (lane & 15);
        int hh = col >> 7, dd = col & 127;
        u32x2 wv;
        wv[0] = pack2(acc[m][n][0], acc[m][n][1]);
        wv[1] = pack2(acc[m][n][2], acc[m][n][3]);
        *(u32x2*)(O + (((size_t)(bb * 16 + hh) * 128 + dd) << 11) + t0) = wv;
      }
    }
    return;
  }

  const bool evenlane = (lane & 1) == 0;
#pragma unroll
  for (int m = 0; m < 8; m++) {
    int rowg = bm * 256 + wm * 128 + m * 16 + (lane >> 4) * 4;
#pragma unroll
    for (int n = 0; n < 4; n += 2) {
#pragma unroll
      for (int j = 0; j < 4; j++) {
        float v0 = acc[m][n][j], v1 = acc[m][n + 1][j];
        float p0 = __shfl_xor(v0, 1);
        float p1 = __shfl_xor(v1, 1);
        int row = rowg + j;
        int b = row >> 11, t = row & 2047;
        int colbase = bn * 256 + wn * 64;
        int col = evenlane ? (colbase + n * 16 + (lane & 15))
                           : (colbase + (n + 1) * 16 + (lane & 15) - 1);
        unsigned int wv = evenlane ? pack2(v0, p0) : pack2(p1, v1);
        int h = col >> 7, d = col & 127;
        *(unsigned int*)(O + (((size_t)(b * 16 + h) * 2048 + t) << 7) + d) = wv;
      }
    }
  }
}

// ---------------------------------------------------------------------------
// Kernel 3: output projection from bf16 attout + bf16 Wo. fp32 out + bias.
// ---------------------------------------------------------------------------
__global__ __launch_bounds__(512, 2) void out_gemm_bf(
    const unsigned short* __restrict__ Ab, const unsigned short* __restrict__ Wb,
    const float* __restrict__ bias, float* __restrict__ Out)
{
  __shared__ unsigned short As[2 * 256 * 64];
  __shared__ unsigned short Bs[2 * 256 * 64];
  const int tid = threadIdx.x;
  const int lane = tid & 63, w = tid >> 6;
  const int wm = w >> 2, wn = w & 3;
  const int bs = xcd_swz256(blockIdx.x);
  const int bm = bs >> 3, bn = bs & 7;

  f32x4 acc[8][4];
#pragma unroll
  for (int m = 0; m < 8; m++)
#pragma unroll
    for (int n = 0; n < 4; n++) acc[m][n] = (f32x4)(0.0f);

  gemm256_bf16(Ab, Wb, As, Bs, bm, bn, tid, acc);

  float bv[4];
#pragma unroll
  for (int n = 0; n < 4; n++) bv[n] = bias[bn * 256 + wn * 64 + n * 16 + (lane & 15)];
  const bool evenlane = (lane & 1) == 0;
#pragma unroll
  for (int m = 0; m < 8; m++) {
    int rowg = bm * 256 + wm * 128 + m * 16 + (lane >> 4) * 4;
#pragma unroll
    for (int n = 0; n < 4; n += 2) {
#pragma unroll
      for (int j = 0; j < 4; j++) {
        float v0 = acc[m][n][j] + bv[n];
        float v1 = acc[m][n + 1][j] + bv[n + 1];
        float p0 = __shfl_xor(v0, 1);
        float p1 = __shfl_xor(v1, 1);
        int row = rowg + j;
        int colbase = bn * 256 + wn * 64;
        int col = evenlane ? (colbase + n * 16 + (lane & 15))
                           : (colbase + (n + 1) * 16 + (lane & 15) - 1);
        f32x2 wv;
        if (evenlane) { wv[0] = v0; wv[1] = p0; }
        else          { wv[0] = p1; wv[1] = v1; }
        *(f32x2*)(Out + (size_t)row * 2048 + col) = wv;
      }
    }
  }
}

// ---------------------------------------------------------------------------
// Fallback kernel 1: fused QKV with in-kernel pack; Q epilogue-scaled by SCQ;
// V out transposed [B,H,D,T].
// ---------------------------------------------------------------------------
__global__ __launch_bounds__(256) void qkv_gemm(
    const float* __restrict__ A0, const float* __restrict__ A1, const float* __restrict__ A2,
    const float* __restrict__ W0, const float* __restrict__ W1, const float* __restrict__ W2,
    unsigned short* __restrict__ O0, unsigned short* __restrict__ O1, unsigned short* __restrict__ O2)
{
  __shared__ unsigned short Asf[128 * 32];
  __shared__ unsigned short Bsf[128 * 32];
  const int z = blockIdx.z;
  const float* A = z == 0 ? A0 : (z == 1 ? A1 : A2);
  const float* W = z == 0 ? W0 : (z == 1 ? W1 : W2);
  unsigned short* O = z == 0 ? O0 : (z == 1 ? O1 : O2);

  const int tid = threadIdx.x;
  const int lane = tid & 63;
  const int wave = tid >> 6;
  const int wm = wave >> 1, wn = wave & 1;
  const int bm = blockIdx.x >> 4, bn = blockIdx.x & 15;

  const int srow = tid >> 1;
  const int shalf = tid & 1;
  const float* Ap = A + (size_t)(bm * 128 + srow) * 2048 + shalf * 16;
  const float* Wp = W + (size_t)(bn * 128 + srow) * 2048 + shalf * 16;
  const int ssw = (srow >> 1) & 3;
  const int aoff0 = srow * 32 + (((shalf * 2 + 0) ^ ssw) << 3);
  const int aoff1 = srow * 32 + (((shalf * 2 + 1) ^ ssw) << 3);

  const int frow = lane & 15;
  const int fk = lane >> 4;

  f32x4 acc[4][4];
#pragma unroll
  for (int m = 0; m < 4; m++)
#pragma unroll
    for (int n = 0; n < 4; n++) acc[m][n] = (f32x4)(0.0f);

  for (int kk = 0; kk < 2048; kk += 32) {
    f32x4 a0 = *(const f32x4*)(Ap + kk);
    f32x4 a1 = *(const f32x4*)(Ap + kk + 4);
    f32x4 a2 = *(const f32x4*)(Ap + kk + 8);
    f32x4 a3 = *(const f32x4*)(Ap + kk + 12);
    f32x4 b0 = *(const f32x4*)(Wp + kk);
    f32x4 b1 = *(const f32x4*)(Wp + kk + 4);
    f32x4 b2 = *(const f32x4*)(Wp + kk + 8);
    f32x4 b3 = *(const f32x4*)(Wp + kk + 12);
    __syncthreads();
    *(u32x4*)(Asf + aoff0) = pack8(a0, a1);
    *(u32x4*)(Asf + aoff1) = pack8(a2, a3);
    *(u32x4*)(Bsf + aoff0) = pack8(b0, b1);
    *(u32x4*)(Bsf + aoff1) = pack8(b2, b3);
    __syncthreads();
    bf16x8 af[4], bfr[4];
#pragma unroll
    for (int m = 0; m < 4; m++) {
      int r = wm * 64 + m * 16 + frow;
      af[m] = *(const bf16x8*)(Asf + r * 32 + ((fk ^ ((r >> 1) & 3)) << 3));
    }
#pragma unroll
    for (int n = 0; n < 4; n++) {
      int r = wn * 64 + n * 16 + frow;
      bfr[n] = *(const bf16x8*)(Bsf + r * 32 + ((fk ^ ((r >> 1) & 3)) << 3));
    }
#pragma unroll
    for (int m = 0; m < 4; m++)
#pragma unroll
      for (int n = 0; n < 4; n++)
        acc[m][n] = __builtin_amdgcn_mfma_f32_16x16x32_bf16(af[m], bfr[n], acc[m][n], 0, 0, 0);
  }

  if (z == 2) {
#pragma unroll
    for (int m = 0; m < 4; m++) {
      int rowg = bm * 128 + wm * 64 + m * 16 + (lane >> 4) * 4;
      int bb = rowg >> 11, t0 = rowg & 2047;
#pragma unroll
      for (int n = 0; n < 4; n++) {
        int col = bn * 128 + wn * 64 + n * 16 + (lane & 15);
        int hh = col >> 7, dd = col & 127;
        u32x2 wv;
        wv[0] = pack2(acc[m][n][0], acc[m][n][1]);
        wv[1] = pack2(acc[m][n][2], acc[m][n][3]);
        *(u32x2*)(O + (((size_t)(bb * 16 + hh) * 128 + dd) << 11) + t0) = wv;
      }
    }
    return;
  }

  const float scl = (z == 0) ? SCQ : 1.0f;
  const bool evenlane = (lane & 1) == 0;
#pragma unroll
  for (int m = 0; m < 4; m++) {
    int rowg = bm * 128 + wm * 64 + m * 16 + (lane >> 4) * 4;
#pragma unroll
    for (int n = 0; n < 4; n += 2) {
#pragma unroll
      for (int j = 0; j < 4; j++) {
        float v0 = acc[m][n][j] * scl, v1 = acc[m][n + 1][j] * scl;
        float p0 = __shfl_xor(v0, 1);
        float p1 = __shfl_xor(v1, 1);
        int row = rowg + j;
        int b = row >> 11, t = row & 2047;
        int colbase = bn * 128 + wn * 64;
        int col = evenlane ? (colbase + n * 16 + (lane & 15))
                           : (colbase + (n + 1) * 16 + (lane & 15) - 1);
        unsigned int wv = evenlane ? pack2(v0, p0) : pack2(p1, v1);
        int h = col >> 7, d = col & 127;
        *(unsigned int*)(O + (((size_t)(b * 16 + h) * 2048 + t) << 7) + d) = wv;
      }
    }
  }
}

// ---------------------------------------------------------------------------
// Kernel 2: flash attention v5 (round-8/13 proven version, restored).
// Log2-space softmax, local-max defer, per-lane partial l, V^T via gload_lds.
// ---------------------------------------------------------------------------
__global__ __launch_bounds__(256, 2) void attn(
    const unsigned short* __restrict__ Qw, const unsigned short* __restrict__ Kw,
    const unsigned short* __restrict__ VwT, unsigned short* __restrict__ attout)
{
  __shared__ unsigned short Ks[2][64 * 128];
  __shared__ unsigned short Vs[2][128 * 64];
  __shared__ unsigned short Ps[128 * 64];

  const int bid = blockIdx.x;
  const int work = ((bid & 7) << 7) | (bid >> 3);
  const int bh = work >> 4;
  const int qtile = work & 15;
  const int b = bh >> 4, h = bh & 15;
  const unsigned short* Qbase = Qw + (size_t)bh * 2048 * 128 + qtile * 128 * 128;
  const unsigned short* Kbase = Kw + (size_t)bh * 2048 * 128;
  const unsigned short* VbaseT = VwT + (size_t)bh * 2048 * 128;
  const int tid = threadIdx.x, lane = tid & 63, w = tid >> 6;
  const int frow = lane & 15, fk = lane >> 4;

  bf16x8 qf[2][4];
#pragma unroll
  for (int m = 0; m < 2; m++)
#pragma unroll
    for (int ks = 0; ks < 4; ks++)
      qf[m][ks] = *(const bf16x8*)(Qbase + (size_t)(w * 32 + m * 16 + frow) * 128 + ks * 32 + fk * 8);

  const int krow_i = lane >> 4;
  const int kslot = lane & 15;
  const int vrow_i = lane >> 3;
  const int vslot = (lane & 7) ^ vrow_i;

  f32x4 o[2][8];
#pragma unroll
  for (int m = 0; m < 2; m++)
#pragma unroll
    for (int n = 0; n < 8; n++) o[m][n] = (f32x4)(0.0f);
  float m_r[2][4], l_p[2][4];
#pragma unroll
  for (int m = 0; m < 2; m++)
#pragma unroll
    for (int j = 0; j < 4; j++) { m_r[m][j] = -INFINITY; l_p[m][j] = 0.f; }
  const float THRL = 11.5f;

  {
#pragma unroll
    for (int i = 0; i < 4; i++) {
      int row = w * 16 + i * 4 + krow_i;
      gload16(Kbase + (size_t)row * 128 + ((kslot ^ (row & 15)) << 3),
              &Ks[0][(w * 16 + i * 4) * 128]);
    }
#pragma unroll
    for (int i = 0; i < 4; i++) {
      int d = w * 32 + i * 8 + vrow_i;
      gload16(VbaseT + (size_t)d * 2048 + vslot * 8,
              &Vs[0][(w * 32 + i * 8) * 64]);
    }
  }

  for (int kt = 0; kt < 32; kt++) {
    const int cur = kt & 1;
    __syncthreads();

    const bool have_next = (kt + 1) < 32;
    if (have_next) {
      const unsigned short* Kt = Kbase + (kt + 1) * 64 * 128;
#pragma unroll
      for (int i = 0; i < 4; i++) {
        int row = w * 16 + i * 4 + krow_i;
        gload16(Kt + (size_t)row * 128 + ((kslot ^ (row & 15)) << 3),
                &Ks[cur ^ 1][(w * 16 + i * 4) * 128]);
      }
#pragma unroll
      for (int i = 0; i < 4; i++) {
        int d = w * 32 + i * 8 + vrow_i;
        gload16(VbaseT + (size_t)d * 2048 + (kt + 1) * 64 + vslot * 8,
                &Vs[cur ^ 1][(w * 32 + i * 8) * 64]);
      }
    }

    f32x4 s[2][4];
    __builtin_amdgcn_s_setprio(1);
#pragma unroll
    for (int n = 0; n < 4; n++) {
      int brow = n * 16 + frow;
      bf16x8 bk = *(const bf16x8*)(&Ks[cur][0] + brow * 128 + ((fk ^ (brow & 15)) << 3));
#pragma unroll
      for (int m = 0; m < 2; m++)
        s[m][n] = __builtin_amdgcn_mfma_f32_16x16x32_bf16(qf[m][0], bk, (f32x4)(0.0f), 0, 0, 0);
    }
#pragma unroll
    for (int ks = 1; ks < 4; ks++) {
#pragma unroll
      for (int n = 0; n < 4; n++) {
        int brow = n * 16 + frow;
        bf16x8 bk = *(const bf16x8*)(&Ks[cur][0] + brow * 128 + (((ks * 4 + fk) ^ (brow & 15)) << 3));
#pragma unroll
        for (int m = 0; m < 2; m++)
          s[m][n] = __builtin_amdgcn_mfma_f32_16x16x32_bf16(qf[m][ks], bk, s[m][n], 0, 0, 0);
      }
    }
    __builtin_amdgcn_s_setprio(0);

#pragma unroll
    for (int m = 0; m < 2; m++) {
#pragma unroll
      for (int j = 0; j < 4; j++) {
        float mx = fmaxf(fmaxf(s[m][0][j], s[m][1][j]), fmaxf(s[m][2][j], s[m][3][j]));
        float mo = m_r[m][j];
        if (!__all(mx - mo <= THRL)) {
          float mnew = fmaxf(mo, rowmax16(mx));
          float f = __builtin_amdgcn_exp2f(mo - mnew);
          m_r[m][j] = mnew;
          l_p[m][j] *= f;
#pragma unroll
          for (int n = 0; n < 8; n++) o[m][n][j] *= f;
        }
        float mm = m_r[m][j];
        float ps = 0.f;
#pragma unroll
        for (int n = 0; n < 4; n++) {
          float p = __builtin_amdgcn_exp2f(s[m][n][j] - mm);
          s[m][n][j] = p;
          ps += p;
        }
        l_p[m][j] += ps;

        int row = w * 32 + m * 16 + (lane >> 4) * 4 + j;
        int swzp = row & 7;
        unsigned prv[4];
#pragma unroll
        for (int n = 0; n < 4; n++) {
          float p = s[m][n][j];
          float ph = dppf<0xB1>(p);
          unsigned pr;
          asm("v_cvt_pk_bf16_f32 %0, %1, %2" : "=v"(pr) : "v"(p), "v"(ph));
          prv[n] = pr;
        }
        if (!(lane & 1)) {
#pragma unroll
          for (int n = 0; n < 4; n++) {
            int col = frow + 16 * n;
            *(unsigned*)((char*)Ps + row * 128 + (((col >> 3) ^ swzp) << 4) + (col & 7) * 2) = prv[n];
          }
        }
      }
    }

    __builtin_amdgcn_s_setprio(1);
#pragma unroll
    for (int ks = 0; ks < 2; ks++) {
      bf16x8 ap[2];
#pragma unroll
      for (int m = 0; m < 2; m++) {
        int arow = w * 32 + m * 16 + frow;
        ap[m] = *(const bf16x8*)((char*)Ps + arow * 128 + (((ks * 4 + fk) ^ (arow & 7)) << 4));
      }
#pragma unroll
      for (int n = 0; n < 8; n++) {
        int vrow = n * 16 + frow;
        bf16x8 bv = *(const bf16x8*)((char*)&Vs[cur][0] + vrow * 128 + (((ks * 4 + fk) ^ (vrow & 7)) << 4));
#pragma unroll
        for (int m = 0; m < 2; m++)
          o[m][n] = __builtin_amdgcn_mfma_f32_16x16x32_bf16(ap[m], bv, o[m][n], 0, 0, 0);
      }
    }
    __builtin_amdgcn_s_setprio(0);
  }

  const bool evenlane = (lane & 1) == 0;
#pragma unroll
  for (int m = 0; m < 2; m++) {
    float inv[4];
#pragma unroll
    for (int j = 0; j < 4; j++) inv[j] = 1.0f / rowsum16(l_p[m][j]);
#pragma unroll
    for (int n = 0; n < 8; n += 2) {
#pragma unroll
      for (int j = 0; j < 4; j++) {
        float v0 = o[m][n][j] * inv[j], v1 = o[m][n + 1][j] * inv[j];
        float p0 = __shfl_xor(v0, 1);
        float p1 = __shfl_xor(v1, 1);
        int tq = qtile * 128 + w * 32 + m * 16 + (lane >> 4) * 4 + j;
        int col = evenlane ? (n * 16 + (lane & 15)) : ((n + 1) * 16 + (lane & 15) - 1);
        unsigned int wv = evenlane ? pack2(v0, p0) : pack2(p1, v1);
        *(unsigned int*)(attout + (size_t)(b * 2048 + tq) * 2048 + h * 128 + col) = wv;
      }
    }
  }
}

// ---------------------------------------------------------------------------
// Fallback kernel 3 (round-1): output projection with in-kernel fp32 W pack.
// ---------------------------------------------------------------------------
__global__ __launch_bounds__(256) void out_gemm(
    const unsigned short* __restrict__ Ab, const float* __restrict__ W,
    const float* __restrict__ bias, float* __restrict__ Out)
{
  __shared__ unsigned short Asf[128 * 32];
  __shared__ unsigned short Bsf[128 * 32];

  const int tid = threadIdx.x;
  const int lane = tid & 63;
  const int wave = tid >> 6;
  const int wm = wave >> 1, wn = wave & 1;
  const int bm = blockIdx.x >> 4, bn = blockIdx.x & 15;

  const int srow = tid >> 1;
  const int shalf = tid & 1;
  const unsigned short* Ap = Ab + (size_t)(bm * 128 + srow) * 2048 + shalf * 16;
  const float* Wp = W + (size_t)(bn * 128 + srow) * 2048 + shalf * 16;
  const int ssw = (srow >> 1) & 3;
  const int aoff0 = srow * 32 + (((shalf * 2 + 0) ^ ssw) << 3);
  const int aoff1 = srow * 32 + (((shalf * 2 + 1) ^ ssw) << 3);

  const int frow = lane & 15;
  const int fk = lane >> 4;

  f32x4 acc[4][4];
#pragma unroll
  for (int m = 0; m < 4; m++)
#pragma unroll
    for (int n = 0; n < 4; n++) acc[m][n] = (f32x4)(0.0f);

  for (int kk = 0; kk < 2048; kk += 32) {
    u32x4 a0 = *(const u32x4*)(Ap + kk);
    u32x4 a1 = *(const u32x4*)(Ap + kk + 8);
    f32x4 b0 = *(const f32x4*)(Wp + kk);
    f32x4 b1 = *(const f32x4*)(Wp + kk + 4);
    f32x4 b2 = *(const f32x4*)(Wp + kk + 8);
    f32x4 b3 = *(const f32x4*)(Wp + kk + 12);
    __syncthreads();
    *(u32x4*)(Asf + aoff0) = a0;
    *(u32x4*)(Asf + aoff1) = a1;
    *(u32x4*)(Bsf + aoff0) = pack8(b0, b1);
    *(u32x4*)(Bsf + aoff1) = pack8(b2, b3);
    __syncthreads();
    bf16x8 af[4], bfr[4];
#pragma unroll
    for (int m = 0; m < 4; m++) {
      int r = wm * 64 + m * 16 + frow;
      af[m] = *(const bf16x8*)(Asf + r * 32 + ((fk ^ ((r >> 1) & 3)) << 3));
    }
#pragma unroll
    for (int n = 0; n < 4; n++) {
      int r = wn * 64 + n * 16 + frow;
      bfr[n] = *(const bf16x8*)(Bsf + r * 32 + ((fk ^ ((r >> 1) & 3)) << 3));
    }
#pragma unroll
    for (int m = 0; m < 4; m++)
#pragma unroll
      for (int n = 0; n < 4; n++)
        acc[m][n] = __builtin_amdgcn_mfma_f32_16x16x32_bf16(af[m], bfr[n], acc[m][n], 0, 0, 0);
  }

  float bv[4];
#pragma unroll
  for (int n = 0; n < 4; n++) bv[n] = bias[bn * 128 + wn * 64 + n * 16 + (lane & 15)];
  const bool evenlane = (lane & 1) == 0;
#pragma unroll
  for (int m = 0; m < 4; m++) {
    int rowg = bm * 128 + wm * 64 + m * 16 + (lane >> 4) * 4;
#pragma unroll
    for (int n = 0; n < 4; n += 2) {
#pragma unroll
      for (int j = 0; j < 4; j++) {
        float v0 = acc[m][n][j] + bv[n];
        float v1 = acc[m][n + 1][j] + bv[n + 1];
        float p0 = __shfl_xor(v0, 1);
        float p1 = __shfl_xor(v1, 1);
        int row = rowg + j;
        int colbase = bn * 128 + wn * 64;
        int col = evenlane ? (colbase + n * 16 + (lane & 15))
                           : (colbase + (n + 1) * 16 + (lane & 15) - 1);
        f32x2 wv;
        if (evenlane) { wv[0] = v0; wv[1] = p0; }
        else          { wv[0] = p1; wv[1] = v1; }
        *(f32x2*)(Out + (size_t)row * 2048 + col) = wv;
      }
    }
  }
}

// ---------------------------------------------------------------------------
extern "C" void kernel_launch(void* const* d_in, const int* in_sizes, int n_in,
                              void* d_out, int out_size, void* d_ws, size_t ws_size,
                              hipStream_t stream)
{
  // setup_inputs order: k, q, v, Wk, Wq, Wv, Wo, bo
  const float* k  = (const float*)d_in[0];
  const float* q  = (const float*)d_in[1];
  const float* v  = (const float*)d_in[2];
  const float* Wk = (const float*)d_in[3];
  const float* Wq = (const float*)d_in[4];
  const float* Wv = (const float*)d_in[5];
  const float* Wo = (const float*)d_in[6];
  const float* bo = (const float*)d_in[7];
  float* out = (float*)d_out;

  const size_t HSZ = (size_t)4 * 16 * 2048 * 128;   // 32 MiB (bf16 elems)

  if (ws_size >= (size_t)224 << 20) {
    unsigned short* Abf = (unsigned short*)d_ws;
    unsigned short* Wbf = Abf + 3 * HSZ;
    unsigned short* Qw  = Wbf + 4 * 4194304;
    unsigned short* Kw  = Qw + HSZ;
    unsigned short* Vw  = Kw + HSZ;       // V stored TRANSPOSED [b,h,d,t]
    unsigned short* Aw  = Abf;

    convAll<<<dim3(32768), 256, 0, stream>>>(q, k, v, Wq, Wk, Wv, Wo, Abf, Wbf);
    qkv_gemm_bf<<<dim3(256, 1, 3), 512, 0, stream>>>(Abf, Wbf, Qw, Kw, Vw);
    attn<<<dim3(1024), 256, 0, stream>>>(Qw, Kw, Vw, Aw);
    out_gemm_bf<<<dim3(256), 512, 0, stream>>>(Aw, Wbf + 3 * 4194304, bo, out);
  } else {
    unsigned short* Qw = (unsigned short*)d_ws;
    unsigned short* Kw = Qw + HSZ;
    unsigned short* Vw = Kw + HSZ;        // transposed V here too
    unsigned short* Aw = Vw + HSZ;
    qkv_gemm<<<dim3(1024, 1, 3), 256, 0, stream>>>(q, k, v, Wq, Wk, Wv, Qw, Kw, Vw);
    attn<<<dim3(1024), 256, 0, stream>>>(Qw, Kw, Vw, Aw);
    out_gemm<<<dim3(1024), 256, 0, stream>>>(Aw, Wo, bo, out);
  }
}